// Round 4
// baseline (267.868 us; speedup 1.0000x reference)
//
#include <hip/hip_runtime.h>
#include <math.h>

#define HW 4096
#define NCH 256
#define DIM 128
#define NPROTO 512
#define L2E 1.4426950408889634f

typedef __attribute__((ext_vector_type(4))) float f32x4;
typedef __attribute__((ext_vector_type(8))) short s16x8;
typedef __attribute__((ext_vector_type(4))) short s16x4;
typedef __attribute__((ext_vector_type(4))) unsigned u32x4;

__device__ __forceinline__ unsigned short f2bf(float f) {
  union { float f; unsigned u; } v; v.f = f;
  unsigned r = v.u + 0x7fffu + ((v.u >> 16) & 1u);
  return (unsigned short)(r >> 16);
}

// ---------------------------------------------------------------------------
// prep: blocks 0..7: prototypes -> bf16 chunked Pr[kc][n][32] (kc = d/32) and
//       pn2s[n] = |gamma| * log2(e) * ||p_n||^2  (pre-scaled for exp2 softmax)
//       blocks 8..9: W -> bf16 chunked Wr[kc][d][32] (kc = c/32)
// 64B rows so MFMA fragments load directly from global:
//   frag(row, koff=8*l4) = base + (kc*ROWS + row)*32 + 8*l4   (bf16 units)
// ---------------------------------------------------------------------------
__global__ __launch_bounds__(256) void prep_kernel(const float* __restrict__ P,
                                                   const float* __restrict__ Wm,
                                                   const float* __restrict__ gptr,
                                                   unsigned short* __restrict__ Pr,
                                                   unsigned short* __restrict__ Wr,
                                                   float* __restrict__ pn2s) {
  const int tid = threadIdx.x;
  if (blockIdx.x < 8) {
    const int n  = blockIdx.x * 64 + (tid >> 2);
    const int qt = tid & 3;
    const float* row = P + n * DIM + qt * 32;
    unsigned short* dst = Pr + ((size_t)qt * NPROTO + n) * 32;
    float ssq = 0.f;
#pragma unroll
    for (int u = 0; u < 8; ++u) {
      f32x4 v = *(const f32x4*)(row + 4 * u);
      ssq += v.x * v.x + v.y * v.y + v.z * v.z + v.w * v.w;
      dst[4 * u + 0] = f2bf(v.x);
      dst[4 * u + 1] = f2bf(v.y);
      dst[4 * u + 2] = f2bf(v.z);
      dst[4 * u + 3] = f2bf(v.w);
    }
    ssq += __shfl_xor(ssq, 1);
    ssq += __shfl_xor(ssq, 2);
    if (qt == 0) pn2s[n] = fabsf(gptr[0]) * L2E * ssq;
  } else {
#pragma unroll
    for (int it = 0; it < 2; ++it) {
      const int p  = (blockIdx.x - 8) * 256 + tid + 512 * it;  // 0..1023
      const int d  = p >> 3;
      const int ch = p & 7;
      const float* src = Wm + d * NCH + 32 * ch;
      unsigned short* dst = Wr + ((size_t)ch * DIM + d) * 32;
#pragma unroll
      for (int u = 0; u < 8; ++u) {
        f32x4 v = *(const f32x4*)(src + 4 * u);
        dst[4 * u + 0] = f2bf(v.x);
        dst[4 * u + 1] = f2bf(v.y);
        dst[4 * u + 2] = f2bf(v.z);
        dst[4 * u + 3] = f2bf(v.w);
      }
    }
  }
}

// x staging helpers. Thread t: fq = t&15 (pixel quad 4fq..4fq+3),
// cg = t>>4 (channel group of 16: 16cg..16cg+15).
__device__ __forceinline__ void x_load(const float* __restrict__ xbase,
                                       int fq, int cg, f32x4 xv[16]) {
#pragma unroll
  for (int p = 0; p < 16; ++p)
    xv[p] = *(const f32x4*)(xbase + (size_t)(16 * cg + p) * HW + 4 * fq);
}

// LDS x layout: x_s[pix][256] bf16 (512B rows), 16B blocks g = ch/8 placed at
// slot = (g&24) | ((g ^ pix ^ (pix>>2)) & 7)  -> uniform 8 lanes/bank-quad
// for both the b128 staging writes and the b128 fragment reads.
__device__ __forceinline__ void x_pack_write(unsigned short* __restrict__ x_s,
                                             int fq, int cg, const f32x4 xv[16]) {
#pragma unroll
  for (int jj = 0; jj < 4; ++jj) {
    const int pix = 4 * fq + jj;
#pragma unroll
    for (int h = 0; h < 2; ++h) {
      const int g = 2 * cg + h;
      const int slot = (g & 24) | ((g ^ pix ^ (pix >> 2)) & 7);
      u32x4 wv;
#pragma unroll
      for (int u = 0; u < 4; ++u) {
        const int p = 8 * h + 2 * u;
        wv[u] = (unsigned)f2bf(xv[p][jj]) | ((unsigned)f2bf(xv[p + 1][jj]) << 16);
      }
      *(u32x4*)(x_s + pix * 256 + slot * 8) = wv;
    }
  }
}

// ---------------------------------------------------------------------------
// fused: 512 blocks x 256 thr (4 waves); block b handles tiles {b, b+512} of
// 64 pixels each, software-pipelined (next tile's x-loads issued under the
// current tile's GEMM2/softmax/store shadow). Per tile:
//   GEMM1  qT = W . xT  (A=W global frags, B=x LDS) -> q bf16 [64][152] LDS
//   GEMM2  wave w = pixels 16w..16w+15 x ALL 512 protos (acc 32 x f32x4)
//   softmax wave-local (register + shfl only, zero barriers, exp2 domain)
//   direct nontemporal f32x4 stores from accumulators
// Only 2 barriers per tile.
// ---------------------------------------------------------------------------
__global__ __launch_bounds__(256, 2) void fused_kernel(const float* __restrict__ x,
                                                       const unsigned short* __restrict__ Wr,
                                                       const float* __restrict__ bias,
                                                       const unsigned short* __restrict__ Pr,
                                                       const float* __restrict__ pn2s,
                                                       const float* __restrict__ gptr,
                                                       float* __restrict__ out) {
  __shared__ __align__(16) unsigned short x_s[64 * 256];  // 32768 B
  __shared__ __align__(16) unsigned short q_s[64 * 152];  // 19456 B (304B rows)

  const int tid  = threadIdx.x;
  const int wave = tid >> 6, lane = tid & 63;
  const int l15 = lane & 15, l4 = lane >> 4;
  const int fq = tid & 15, cg = tid >> 4;
  const float g2 = 2.f * fabsf(gptr[0]) * L2E;

  // ---- prologue: stage tile b
  {
    const int p0 = blockIdx.x * 64;
    const float* xbase = x + (size_t)(p0 >> 12) * NCH * HW + (p0 & 4095);
    f32x4 xv[16];
    x_load(xbase, fq, cg, xv);
    x_pack_write(x_s, fq, cg, xv);
  }
  __syncthreads();

#pragma unroll
  for (int tt = 0; tt < 2; ++tt) {
    const int tile = blockIdx.x + 512 * tt;
    const int p0   = tile * 64;
    const int nimg = p0 >> 12;
    const int hw0  = p0 & 4095;

    // ---- GEMM1: wave w -> d-tiles {2w, 2w+1}, all 4 pixel-tiles
    {
      f32x4 qacc[2][4];
#pragma unroll
      for (int mm = 0; mm < 2; ++mm)
#pragma unroll
        for (int nt = 0; nt < 4; ++nt)
#pragma unroll
          for (int r = 0; r < 4; ++r) qacc[mm][nt][r] = 0.f;

#pragma unroll
      for (int kc = 0; kc < 8; ++kc) {
        s16x8 xb[4];
#pragma unroll
        for (int nt = 0; nt < 4; ++nt) {
          const int pix  = 16 * nt + l15;
          const int gblk = 4 * kc + l4;
          const int slot = (gblk & 24) | ((gblk ^ pix ^ (pix >> 2)) & 7);
          xb[nt] = *(const s16x8*)(x_s + pix * 256 + slot * 8);
        }
#pragma unroll
        for (int mm = 0; mm < 2; ++mm) {
          s16x8 wfr = *(const s16x8*)(Wr + (size_t)(kc * DIM + 16 * (2 * wave + mm) + l15) * 32 + 8 * l4);
#pragma unroll
          for (int nt = 0; nt < 4; ++nt)
            qacc[mm][nt] = __builtin_amdgcn_mfma_f32_16x16x32_bf16(wfr, xb[nt], qacc[mm][nt], 0, 0, 0);
        }
      }
      // epilogue: D row = d_local = 4*l4+r, col = pix = 16nt+l15
#pragma unroll
      for (int mm = 0; mm < 2; ++mm) {
        const int d0 = 16 * (2 * wave + mm) + 4 * l4;
        f32x4 bv = *(const f32x4*)(bias + d0);
#pragma unroll
        for (int nt = 0; nt < 4; ++nt) {
          const int pix = 16 * nt + l15;
          s16x4 o;
#pragma unroll
          for (int r = 0; r < 4; ++r) o[r] = (short)f2bf(qacc[mm][nt][r] + bv[r]);
          *(s16x4*)(q_s + pix * 152 + d0) = o;
        }
      }
    }
    __syncthreads();  // q_s valid; x_s free for overwrite

    // ---- GEMM2: wave w = pixels 16w..16w+15, all 512 protos
    s16x8 afr[4];
#pragma unroll
    for (int kc = 0; kc < 4; ++kc)
      afr[kc] = *(const s16x8*)(q_s + (16 * wave + l15) * 152 + 32 * kc + 8 * l4);

    f32x4 acc[32];
#pragma unroll
    for (int j = 0; j < 32; ++j)
#pragma unroll
      for (int r = 0; r < 4; ++r) acc[j][r] = 0.f;

#pragma unroll
    for (int kc = 0; kc < 4; ++kc) {
      const unsigned short* pb = Pr + (size_t)(kc * NPROTO + l15) * 32 + 8 * l4;
#pragma unroll
      for (int j = 0; j < 32; ++j) {
        s16x8 bfr = *(const s16x8*)(pb + (size_t)(16 * j) * 32);
        acc[j] = __builtin_amdgcn_mfma_f32_16x16x32_bf16(afr[kc], bfr, acc[j], 0, 0, 0);
      }
    }

    // ---- issue next tile's x loads (held in regs through softmax+stores)
    f32x4 xv[16];
    if (tt == 0) {
      const int pn = (blockIdx.x + 512) * 64;
      const float* xbase = x + (size_t)(pn >> 12) * NCH * HW + (pn & 4095);
      x_load(xbase, fq, cg, xv);
    }

    // ---- wave-local softmax (exp2 domain). lane (l15,l4), reg r holds
    //      pix = 16w + 4*l4 + r, proto = 16j + l15.
#pragma unroll
    for (int j = 0; j < 32; ++j) {
      const float p2 = pn2s[16 * j + l15];
#pragma unroll
      for (int r = 0; r < 4; ++r) acc[j][r] = g2 * acc[j][r] - p2;
    }
    f32x4 mx = acc[0];
#pragma unroll
    for (int j = 1; j < 32; ++j)
#pragma unroll
      for (int r = 0; r < 4; ++r) mx[r] = fmaxf(mx[r], acc[j][r]);
#pragma unroll
    for (int s = 1; s < 16; s <<= 1)
#pragma unroll
      for (int r = 0; r < 4; ++r) mx[r] = fmaxf(mx[r], __shfl_xor(mx[r], s));
    f32x4 sm = {0.f, 0.f, 0.f, 0.f};
#pragma unroll
    for (int j = 0; j < 32; ++j)
#pragma unroll
      for (int r = 0; r < 4; ++r) {
        const float e = exp2f(acc[j][r] - mx[r]);
        acc[j][r] = e;
        sm[r] += e;
      }
#pragma unroll
    for (int s = 1; s < 16; s <<= 1)
#pragma unroll
      for (int r = 0; r < 4; ++r) sm[r] += __shfl_xor(sm[r], s);
    f32x4 inv;
#pragma unroll
    for (int r = 0; r < 4; ++r) inv[r] = 1.0f / sm[r];

    // ---- direct stores: plane = 16j+l15, pixels 16w+4*l4 .. +3 contiguous
    const size_t ob = (size_t)nimg * NPROTO * HW + hw0 + 16 * wave + 4 * l4;
#pragma unroll
    for (int j = 0; j < 32; ++j) {
      f32x4 o;
#pragma unroll
      for (int r = 0; r < 4; ++r) o[r] = acc[j][r] * inv[r];
      __builtin_nontemporal_store(o, (f32x4*)(out + ob + (size_t)(16 * j + l15) * HW));
    }

    // ---- pack+write next tile's x, then single end-of-tile barrier
    if (tt == 0) {
      x_pack_write(x_s, fq, cg, xv);
      __syncthreads();
    }
  }
}

extern "C" void kernel_launch(void* const* d_in, const int* in_sizes, int n_in,
                              void* d_out, int out_size, void* d_ws, size_t ws_size,
                              hipStream_t stream) {
  const float* x     = (const float*)d_in[0];
  const float* Wm    = (const float*)d_in[1];
  const float* bias  = (const float*)d_in[2];
  const float* prot  = (const float*)d_in[3];
  const float* gamma = (const float*)d_in[4];
  float* out = (float*)d_out;

  // ws: Pr 128KiB | Wr 64KiB | pn2s 2KiB
  unsigned short* P_ws  = (unsigned short*)d_ws;
  unsigned short* W_ws  = (unsigned short*)((char*)d_ws + 131072);
  float*          pn2_w = (float*)((char*)d_ws + 131072 + 65536);

  prep_kernel<<<10, 256, 0, stream>>>(prot, Wm, gamma, P_ws, W_ws, pn2_w);
  fused_kernel<<<512, 256, 0, stream>>>(x, W_ws, bias, P_ws, pn2_w, gamma, out);
}